// Round 9
// baseline (743.467 us; speedup 1.0000x reference)
//
#include <hip/hip_runtime.h>

#define KP 2048
#define DD 1024
#define DF 128
#define NH 16
#define DKK 64
#define NSS 18
#define NCC 19
#define NCH 4
#define CHUNK 512
#define SPLK 16
#define NBLK 512

typedef __attribute__((ext_vector_type(8))) short short8;
typedef __attribute__((ext_vector_type(4))) short short4_t;
typedef __attribute__((ext_vector_type(4))) float f32x4;

__device__ __forceinline__ short f2bf(float x){
    unsigned u = __float_as_uint(x);
    u += 0x7fffu + ((u >> 16) & 1u);   // round-to-nearest-even
    return (short)(u >> 16);
}

__device__ __forceinline__ void gl2lds16(const void* g, void* l){
    __builtin_amdgcn_global_load_lds((const __attribute__((address_space(1))) void*)g,
                                     (__attribute__((address_space(3))) void*)l, 16, 0, 0);
}

// software grid barrier: monotonic counter, device(agent)-scope atomics.
// All NBLK blocks are co-resident (launch_bounds(256,2) x 256 CUs >= NBLK).
__device__ __forceinline__ void gsync(unsigned* bar, unsigned target, int t){
    __syncthreads();
    if (t == 0){
        __threadfence();   // release: make this block's writes device-visible
        __hip_atomic_fetch_add(bar, 1u, __ATOMIC_ACQ_REL, __HIP_MEMORY_SCOPE_AGENT);
        while (__hip_atomic_load(bar, __ATOMIC_ACQUIRE, __HIP_MEMORY_SCOPE_AGENT) < target)
            __builtin_amdgcn_s_sleep(2);
    }
    __syncthreads();
    __threadfence();       // acquire: invalidate stale cache lines
}

struct Params {
    const float *size_scores, *srn, *sem, *app, *mean;
    const float *w_rank, *b_rank, *w_roi, *b_roi, *Wq, *Wk, *Wv, *w_logit, *b_logit;
    float* out;
    float* box; int* label; double* probd; double* keyd; int* order; float* sprob;
    short* wcat; short* qkT; short* uT; short* e_bf; short* qk_bf;
    float* vwT; float* pl; float* pwl; short* af; float* es;
    unsigned* bar;
};

// ---- LDS-staged 64x64 bf16 GEMM tile (BK=64), smem = 16 KB ----
__device__ __forceinline__ void gemm_tile(const short* __restrict__ A,
                                          const short* __restrict__ BT,
                                          void* __restrict__ C,
                                          int lda, int ldb, int N,
                                          int klen, int kb, int m0, int n0,
                                          int mode, char* smemc, int tid){
    short* alds = (short*)smemc;
    short* blds = alds + 4096;
    int w = tid >> 6, lane = tid & 63;
    int quad = lane >> 4, l16 = lane & 15;

    int p0 = w * 64 + lane;
    int r0 = p0 >> 3, q0 = ((p0 & 7) ^ (r0 & 7)) * 8;
    int p1 = p0 + 256;
    int r1 = p1 >> 3, q1 = ((p1 & 7) ^ (r1 & 7)) * 8;
    short* adst0 = alds + w * 512;
    short* adst1 = alds + 2048 + w * 512;
    short* bdst0 = blds + w * 512;
    short* bdst1 = blds + 2048 + w * 512;
    const short* asrc0 = A + (size_t)(m0 + r0) * lda + kb + q0;
    const short* asrc1 = A + (size_t)(m0 + r1) * lda + kb + q1;
    const short* bsrc0 = BT + (size_t)(n0 + r0) * ldb + kb + q0;
    const short* bsrc1 = BT + (size_t)(n0 + r1) * ldb + kb + q1;

    f32x4 acc[4];
    for (int c = 0; c < 4; c++) acc[c] = (f32x4){0.f, 0.f, 0.f, 0.f};

    for (int kt = 0; kt < klen; kt += 64){
        __syncthreads();
        gl2lds16(asrc0 + kt, adst0);
        gl2lds16(asrc1 + kt, adst1);
        gl2lds16(bsrc0 + kt, bdst0);
        gl2lds16(bsrc1 + kt, bdst1);
        __syncthreads();
        int arow = w * 16 + l16;
        #pragma unroll
        for (int s = 0; s < 2; s++){
            short8 a = *(const short8*)(alds + arow * 64 + (((s * 4 + quad) ^ (l16 & 7)) * 8));
            #pragma unroll
            for (int c = 0; c < 4; c++){
                int brow = c * 16 + l16;
                short8 b = *(const short8*)(blds + brow * 64 + (((s * 4 + quad) ^ (l16 & 7)) * 8));
                acc[c] = __builtin_amdgcn_mfma_f32_16x16x32_bf16(a, b, acc[c], 0, 0, 0);
            }
        }
    }
    __syncthreads();   // protect LDS before reuse
    int mrow = m0 + w * 16 + quad * 4;
    #pragma unroll
    for (int c = 0; c < 4; c++){
        #pragma unroll
        for (int r = 0; r < 4; r++){
            size_t idx = (size_t)(mrow + r) * N + n0 + c * 16 + l16;
            if (mode == 2) ((short*)C)[idx] = f2bf(acc[c][r]);
            else ((float*)C)[idx] = acc[c][r];
        }
    }
}

__global__ __launch_bounds__(256, 2) void mega_kernel(Params p){
    int bid = blockIdx.x, t = threadIdx.x;
    __shared__ __align__(16) char smem[17024];

    // ================= phase 0: prep =================
    {
        int k = bid * 256 + t;
        if (bid < 8 && k < KP){
            const float* ss = p.size_scores + k * NSS;
            int psc = 0; float bs = ss[0];
            for (int s = 1; s < NSS; s++){ float v = ss[s]; if (v > bs){ bs = v; psc = s; } }
            for (int c = 0; c < 3; c++){
                float m = p.mean[psc * 3 + c];
                float r = p.srn[k * (NSS * 3) + psc * 3 + c];
                p.box[k * 3 + c] = m + r * m;
            }
            const float* cs = p.sem + k * NCC;
            double mx = (double)cs[0]; int lab = 0;
            for (int c = 1; c < NCC; c++){ double v = (double)cs[c]; if (v > mx){ mx = v; lab = c; } }
            double sum = 0.0;
            for (int c = 0; c < NCC; c++) sum += exp((double)cs[c] - mx);
            double prob = 1.0 / sum;
            p.probd[k] = prob;
            p.label[k] = lab;
            p.keyd[k]  = (lab > 0) ? prob : -1.0;
        }
    }
    gsync(p.bar, NBLK * 1, t);

    // ================= phase 1: stable descending rank + scatter outputs =================
    {
        int* red = (int*)smem;
        const double2* k2 = (const double2*)p.keyd;
        for (int i = bid; i < KP; i += NBLK){
            double ki = p.keyd[i];
            int r = 0;
            #pragma unroll
            for (int pp = 0; pp < KP / 2 / 256; pp++){
                int idx2 = pp * 256 + t;
                double2 kj = k2[idx2];
                int j0 = idx2 * 2;
                r += (int)(kj.x > ki) + (int)((kj.x == ki) & (j0 < i));
                r += (int)(kj.y > ki) + (int)((kj.y == ki) & (j0 + 1 < i));
            }
            #pragma unroll
            for (int off = 32; off > 0; off >>= 1) r += __shfl_down(r, off);
            if ((t & 63) == 0) red[t >> 6] = r;
            __syncthreads();
            if (t == 0){
                int rk = red[0] + red[1] + red[2] + red[3];
                p.order[rk] = i;
                p.sprob[rk] = (p.label[i] > 0) ? (float)p.probd[i] : 0.f;
                p.out[KP + rk] = (float)(p.label[i] - 1);
                p.out[2 * KP + 3 * rk + 0] = p.box[i * 3 + 0];
                p.out[2 * KP + 3 * rk + 1] = p.box[i * 3 + 1];
                p.out[2 * KP + 3 * rk + 2] = p.box[i * 3 + 2];
            }
            __syncthreads();
        }
    }
    gsync(p.bar, NBLK * 2, t);

    // ================= phase 2: af (emb | gathered features) + weight prep =================
    {
        for (int pos = bid; pos < KP; pos += NBLK){
            int ord = p.order[pos];
            float4 v = ((const float4*)(p.app + (size_t)ord * DD))[t];
            short4_t gg = { f2bf(v.x), f2bf(v.y), f2bf(v.z), f2bf(v.w) };
            *(short4_t*)(p.af + (size_t)pos * 2048 + 1024 + t * 4) = gg;
            short4_t e;
            #pragma unroll
            for (int i = 0; i < 4; i++){
                int j = t * 4 + i, jj = j & 511;
                float inv = exp2f(-(float)jj * 0.0194644224310197f);  // log2(1000)/512
                float arg = (float)pos * inv;
                e[i] = f2bf((j < 512) ? __sinf(arg) : __cosf(arg));
            }
            *(short4_t*)(p.af + (size_t)pos * 2048 + t * 4) = e;
        }
        int b = bid;
        if (b >= 128 && b < 192){   // u[h][f] = sum_e Wv[h][f][e]*wl[h*64+e]
            int i = b - 128;
            int h = i >> 2;
            int f = ((i & 3) << 8) + t;
            const float* wv = p.Wv + (size_t)h * DD * DKK + (size_t)f * DKK;
            const float* wlh = p.w_logit + h * DKK;
            float s = 0.f;
            #pragma unroll
            for (int e = 0; e < DKK; e++) s += wv[e] * wlh[e];
            p.uT[h * DD + f] = f2bf(s);
        } else if (b < 128){        // LDS-tiled transposes
            float (*tile)[65] = (float(*)[65])smem;
            const float* src; short* dst; int sstride, dstride, r0, c0, doff;
            float scale = 1.0f;
            if (b < 32){        src = p.w_rank; dst = p.wcat; sstride = DF; dstride = 2048;
                                r0 = (b >> 1) * 64; c0 = (b & 1) * 64; doff = 0; }
            else if (b < 64){   int i = b - 32; src = p.w_roi; dst = p.wcat; sstride = DF; dstride = 2048;
                                r0 = (i >> 1) * 64; c0 = (i & 1) * 64; doff = 1024; }
            else if (b < 96){   int i = b - 64; int h = i >> 1;
                                src = p.Wq + (size_t)h * DF * DKK; dst = p.qkT + (size_t)h * DKK * DF;
                                sstride = DKK; dstride = DF; r0 = (i & 1) * 64; c0 = 0; doff = 0;
                                scale = 0.125f; }   // fold 1/sqrt(dk) into q
            else {              int i = b - 96; int h = i >> 1;
                                src = p.Wk + (size_t)h * DF * DKK; dst = p.qkT + (size_t)(1024 + h * DKK) * DF;
                                sstride = DKK; dstride = DF; r0 = (i & 1) * 64; c0 = 0; doff = 0; }
            int tx = t & 63, ty = t >> 6;
            #pragma unroll
            for (int pp = 0; pp < 16; pp++){
                int r = pp * 4 + ty;
                tile[r][tx] = src[(size_t)(r0 + r) * sstride + c0 + tx];
            }
            __syncthreads();
            #pragma unroll
            for (int pp = 0; pp < 16; pp++){
                int r = pp * 4 + ty;
                dst[(size_t)(c0 + r) * dstride + doff + r0 + tx] = f2bf(tile[tx][r] * scale);
            }
        }
    }
    gsync(p.bar, NBLK * 3, t);

    // ================= phase 3: e-GEMM  es[z] = af @ wcat^T  (K=2048, split-K=16) =================
    {
        #pragma unroll
        for (int it = 0; it < 2; it++){
            int vb = bid + it * NBLK;
            int m0 = (vb & 31) * 64, n0 = ((vb >> 5) & 1) * 64, z = vb >> 6;
            gemm_tile(p.af, p.wcat, p.es + (size_t)z * KP * DF,
                      2048, 2048, DF, 2048 / SPLK, z * (2048 / SPLK), m0, n0, 0, smem, t);
        }
    }
    gsync(p.bar, NBLK * 4, t);

    // ================= phase 4: combine e slabs (+biases -> bf16)  +  vw = sf @ u =================
    {
        if (bid < 256){
            int base = (bid * 256 + t) * 4;
            int n = base & (DF - 1);
            float4 s = *(const float4*)(p.es + base);
            #pragma unroll
            for (int c = 1; c < SPLK; c++){
                float4 tt = *(const float4*)(p.es + (size_t)c * KP * DF + base);
                s.x += tt.x; s.y += tt.y; s.z += tt.z; s.w += tt.w;
            }
            float4 br = *(const float4*)(p.b_rank + n);
            float4 bo = *(const float4*)(p.b_roi + n);
            short4_t o = { f2bf(s.x + br.x + bo.x), f2bf(s.y + br.y + bo.y),
                           f2bf(s.z + br.z + bo.z), f2bf(s.w + br.w + bo.w) };
            *(short4_t*)(p.e_bf + base) = o;
        } else if (bid < 256 + KP / 64){
            int vb = bid - 256;
            int w = t >> 6, lane = t & 63, quad = lane >> 4, l16 = lane & 15;
            int m0 = vb * 64 + w * 16;
            f32x4 acc = (f32x4){0.f, 0.f, 0.f, 0.f};
            const short* arow = p.af + (size_t)(m0 + l16) * 2048 + 1024 + quad * 8;
            const short* brow = p.uT + (size_t)l16 * DD + quad * 8;
            for (int k0 = 0; k0 < DD; k0 += 32){
                short8 a = *(const short8*)(arow + k0);
                short8 b = *(const short8*)(brow + k0);
                acc = __builtin_amdgcn_mfma_f32_16x16x32_bf16(a, b, acc, 0, 0, 0);
            }
            #pragma unroll
            for (int r = 0; r < 4; r++)
                p.vwT[(size_t)l16 * KP + m0 + quad * 4 + r] = acc[r];
        }
    }
    gsync(p.bar, NBLK * 5, t);

    // ================= phase 5: qk-GEMM  [q|k] = e @ qkT^T (K=128, bf16 out) =================
    {
        #pragma unroll
        for (int it = 0; it < 2; it++){
            int vb = bid + it * NBLK;
            int m0 = (vb & 31) * 64, n0 = (vb >> 5) * 64;
            gemm_tile(p.e_bf, p.qkT, p.qk_bf, DF, DF, 2048, DF, 0, m0, n0, 2, smem, t);
        }
    }
    gsync(p.bar, NBLK * 6, t);

    // ================= phase 6: attention (QK^T, exp, two weighted row-sums) =================
    {
        int w = t >> 6, lane = t & 63, quad = lane >> 4, l16 = lane & 15;
        short* klds = (short*)smem;
        int seg0 = w * 128 + lane;
        int row0 = seg0 >> 3, c80 = (seg0 & 7) ^ (row0 & 7);
        int seg1 = seg0 + 64;
        int row1 = seg1 >> 3, c81 = (seg1 & 7) ^ (row1 & 7);
        short* kl0 = klds + (size_t)(w * 128) * 8;
        short* kl1 = klds + (size_t)(w * 128 + 64) * 8;

        #pragma unroll
        for (int it = 0; it < 2; it++){
            int job = bid + it * NBLK;
            int qt = job & 15, h = (job >> 4) & 15, ch = job >> 8;
            int qb = qt * 128;

            short8 aq[2][2];
            #pragma unroll
            for (int tt = 0; tt < 2; tt++){
                const short* qrow = p.qk_bf + (size_t)(qb + tt * 64 + w * 16 + l16) * 2048 + h * DKK;
                aq[tt][0] = *(const short8*)(qrow + quad * 8);
                aq[tt][1] = *(const short8*)(qrow + 32 + quad * 8);
            }
            float lpart[2][4] = {{0.f,0.f,0.f,0.f},{0.f,0.f,0.f,0.f}};
            float wpart[2][4] = {{0.f,0.f,0.f,0.f},{0.f,0.f,0.f,0.f}};

            for (int m0 = ch * CHUNK; m0 < (ch + 1) * CHUNK; m0 += 64){
                __syncthreads();
                gl2lds16(p.qk_bf + (size_t)(m0 + row0) * 2048 + 1024 + h * DKK + c80 * 8, kl0);
                gl2lds16(p.qk_bf + (size_t)(m0 + row1) * 2048 + 1024 + h * DKK + c81 * 8, kl1);
                float vwv[4];
                #pragma unroll
                for (int c = 0; c < 4; c++)
                    vwv[c] = p.vwT[(size_t)h * KP + m0 + c * 16 + l16];
                __syncthreads();

                #pragma unroll
                for (int tt = 0; tt < 2; tt++){
                    #pragma unroll
                    for (int c = 0; c < 4; c++){
                        int r = c * 16 + l16, sw = r & 7;
                        short8 b0 = *(const short8*)(klds + r * 64 + (quad ^ sw) * 8);
                        short8 b1 = *(const short8*)(klds + r * 64 + ((quad + 4) ^ sw) * 8);
                        f32x4 acc = (f32x4){0.f, 0.f, 0.f, 0.f};
                        acc = __builtin_amdgcn_mfma_f32_16x16x32_bf16(aq[tt][0], b0, acc, 0, 0, 0);
                        acc = __builtin_amdgcn_mfma_f32_16x16x32_bf16(aq[tt][1], b1, acc, 0, 0, 0);
                        #pragma unroll
                        for (int rr = 0; rr < 4; rr++){
                            float e = __expf(acc[rr]);
                            lpart[tt][rr] += e;
                            wpart[tt][rr] += e * vwv[c];
                        }
                    }
                }
            }
            __syncthreads();
            #pragma unroll
            for (int tt = 0; tt < 2; tt++){
                #pragma unroll
                for (int rr = 0; rr < 4; rr++){
                    float v = lpart[tt][rr], x = wpart[tt][rr];
                    v += __shfl_xor(v, 1); x += __shfl_xor(x, 1);
                    v += __shfl_xor(v, 2); x += __shfl_xor(x, 2);
                    v += __shfl_xor(v, 4); x += __shfl_xor(x, 4);
                    v += __shfl_xor(v, 8); x += __shfl_xor(x, 8);
                    lpart[tt][rr] = v; wpart[tt][rr] = x;
                }
                if (l16 == 0){
                    int qr0 = qb + tt * 64 + w * 16;
                    #pragma unroll
                    for (int rr = 0; rr < 4; rr++){
                        size_t idx = ((size_t)ch * NH + h) * KP + qr0 + quad * 4 + rr;
                        p.pl[idx]  = lpart[tt][rr];
                        p.pwl[idx] = wpart[tt][rr];
                    }
                }
            }
        }
    }
    gsync(p.bar, NBLK * 7, t);

    // ================= phase 7: final logit + score =================
    {
        float* red = (float*)smem;
        float* hsum = red + 4;
        for (int pos = bid; pos < KP; pos += NBLK){
            int ord = p.order[pos];
            float4 a = *(const float4*)(p.app + (size_t)ord * DD + t * 4);
            float4 wv = *(const float4*)(p.w_logit + t * 4);
            float partial = a.x * wv.x + a.y * wv.y + a.z * wv.z + a.w * wv.w;
            for (int off = 32; off > 0; off >>= 1) partial += __shfl_down(partial, off);
            if ((t & 63) == 0) red[t >> 6] = partial;
            if (t < NH){
                float l = 0.f, x = 0.f;
                #pragma unroll
                for (int c = 0; c < NCH; c++){
                    size_t idx = ((size_t)c * NH + t) * KP + pos;
                    l += p.pl[idx]; x += p.pwl[idx];
                }
                hsum[t] = x / l;
            }
            __syncthreads();
            if (t == 0){
                float logit = red[0] + red[1] + red[2] + red[3] + p.b_logit[0];
                #pragma unroll
                for (int h = 0; h < NH; h++) logit += hsum[h];
                float s1 = 1.f / (1.f + __expf(-logit));
                p.out[pos] = s1 * p.sprob[pos];
            }
            __syncthreads();
        }
    }
}

extern "C" void kernel_launch(void* const* d_in, const int* in_sizes, int n_in,
                              void* d_out, int out_size, void* d_ws, size_t ws_size,
                              hipStream_t stream){
    (void)in_sizes; (void)n_in; (void)out_size; (void)ws_size;
    char* ws = (char*)d_ws;
    size_t off = 0;
    auto alloc = [&](size_t n) -> char* {
        char* pp = ws + off;
        off = (off + n + 255) & ~(size_t)255;
        return pp;
    };
    Params p;
    p.size_scores = (const float*)d_in[0];
    p.srn     = (const float*)d_in[1];
    p.sem     = (const float*)d_in[2];
    p.app     = (const float*)d_in[3];
    p.mean    = (const float*)d_in[4];
    p.w_rank  = (const float*)d_in[5];
    p.b_rank  = (const float*)d_in[6];
    p.w_roi   = (const float*)d_in[7];
    p.b_roi   = (const float*)d_in[8];
    p.Wq      = (const float*)d_in[9];
    p.Wk      = (const float*)d_in[10];
    p.Wv      = (const float*)d_in[11];
    p.w_logit = (const float*)d_in[12];
    p.b_logit = (const float*)d_in[13];
    p.out     = (float*)d_out;
    p.bar    = (unsigned*) alloc(256);
    p.box    = (float*) alloc((size_t)KP * 3 * 4);
    p.label  = (int*)   alloc((size_t)KP * 4);
    p.probd  = (double*)alloc((size_t)KP * 8);
    p.keyd   = (double*)alloc((size_t)KP * 8);
    p.order  = (int*)   alloc((size_t)KP * 4);
    p.sprob  = (float*) alloc((size_t)KP * 4);
    p.wcat   = (short*) alloc((size_t)DF * 2048 * 2);
    p.qkT    = (short*) alloc((size_t)2048 * DF * 2);
    p.uT     = (short*) alloc((size_t)NH * DD * 2);
    p.e_bf   = (short*) alloc((size_t)KP * DF * 2);
    p.qk_bf  = (short*) alloc((size_t)KP * 2048 * 2);
    p.vwT    = (float*) alloc((size_t)NH * KP * 4);
    p.pl     = (float*) alloc((size_t)NCH * NH * KP * 4);
    p.pwl    = (float*) alloc((size_t)NCH * NH * KP * 4);
    p.af     = (short*) alloc((size_t)KP * 2048 * 2);
    p.es     = (float*) alloc((size_t)SPLK * KP * DF * 4);

    hipMemsetAsync(p.bar, 0, 256, stream);   // barrier counter must start at 0 (ws is poisoned)
    mega_kernel<<<NBLK, 256, 0, stream>>>(p);
}

// Round 10
// 467.362 us; speedup vs baseline: 1.5908x; 1.5908x over previous
//
#include <hip/hip_runtime.h>

#define KP 2048
#define DD 1024
#define DF 128
#define NH 16
#define DKK 64
#define NSS 18
#define NCC 19
#define NCH 4
#define CHUNK 512
#define SPLK 16
#define NBLK 512

typedef __attribute__((ext_vector_type(8))) short short8;
typedef __attribute__((ext_vector_type(4))) short short4_t;
typedef __attribute__((ext_vector_type(4))) float f32x4;

__device__ __forceinline__ short f2bf(float x){
    unsigned u = __float_as_uint(x);
    u += 0x7fffu + ((u >> 16) & 1u);   // round-to-nearest-even
    return (short)(u >> 16);
}

__device__ __forceinline__ void gl2lds16(const void* g, void* l){
    __builtin_amdgcn_global_load_lds((const __attribute__((address_space(1))) void*)g,
                                     (__attribute__((address_space(3))) void*)l, 16, 0, 0);
}

// Distributed grid barrier: per-block arrival flags + per-block release flags.
// NO same-address contention: arrivals are 512 distinct stores; block 0 aggregates;
// releases are 512 distinct stores; each block spins only on its own slot.
// Monotonic phase stamps (no reset / no ABA). Cross-XCD visibility via
// release-fence->store / load->acquire-fence chains (G16).
__device__ __forceinline__ void gsync(unsigned* arr, unsigned* rel, unsigned phase,
                                      int bid, int t){
    __syncthreads();
    if (bid == 0){
        int i1 = t, i2 = t + 256;
        if (i1 > 0)
            while (__hip_atomic_load(arr + i1, __ATOMIC_RELAXED, __HIP_MEMORY_SCOPE_AGENT) < phase)
                __builtin_amdgcn_s_sleep(1);
        if (i2 < NBLK)
            while (__hip_atomic_load(arr + i2, __ATOMIC_RELAXED, __HIP_MEMORY_SCOPE_AGENT) < phase)
                __builtin_amdgcn_s_sleep(1);
        __syncthreads();           // all arrivals observed by the whole block
        __threadfence();           // acquire arrivals' data + release our own writes
        __hip_atomic_store(rel + i1, phase, __ATOMIC_RELAXED, __HIP_MEMORY_SCOPE_AGENT);
        if (i2 < NBLK)
            __hip_atomic_store(rel + i2, phase, __ATOMIC_RELAXED, __HIP_MEMORY_SCOPE_AGENT);
    } else {
        if (t == 0){
            __threadfence();       // release this block's phase writes
            __hip_atomic_store(arr + bid, phase, __ATOMIC_RELAXED, __HIP_MEMORY_SCOPE_AGENT);
            while (__hip_atomic_load(rel + bid, __ATOMIC_RELAXED, __HIP_MEMORY_SCOPE_AGENT) < phase)
                __builtin_amdgcn_s_sleep(1);
        }
        __syncthreads();
        __threadfence();           // acquire all other blocks' writes
    }
}

struct Params {
    const float *size_scores, *srn, *sem, *app, *mean;
    const float *w_rank, *b_rank, *w_roi, *b_roi, *Wq, *Wk, *Wv, *w_logit, *b_logit;
    float* out;
    float* box; int* label; double* probd; double* keyd; int* order; float* sprob;
    short* wcat; short* qkT; short* uT; short* e_bf; short* qk_bf;
    float* vwT; float* pl; float* pwl; short* af; float* es;
    unsigned* arr; unsigned* rel;
};

// ---- LDS-staged 64x64 bf16 GEMM tile (BK=64), smem = 16 KB ----
__device__ __forceinline__ void gemm_tile(const short* __restrict__ A,
                                          const short* __restrict__ BT,
                                          void* __restrict__ C,
                                          int lda, int ldb, int N,
                                          int klen, int kb, int m0, int n0,
                                          int mode, char* smemc, int tid){
    short* alds = (short*)smemc;
    short* blds = alds + 4096;
    int w = tid >> 6, lane = tid & 63;
    int quad = lane >> 4, l16 = lane & 15;

    int p0 = w * 64 + lane;
    int r0 = p0 >> 3, q0 = ((p0 & 7) ^ (r0 & 7)) * 8;
    int p1 = p0 + 256;
    int r1 = p1 >> 3, q1 = ((p1 & 7) ^ (r1 & 7)) * 8;
    short* adst0 = alds + w * 512;
    short* adst1 = alds + 2048 + w * 512;
    short* bdst0 = blds + w * 512;
    short* bdst1 = blds + 2048 + w * 512;
    const short* asrc0 = A + (size_t)(m0 + r0) * lda + kb + q0;
    const short* asrc1 = A + (size_t)(m0 + r1) * lda + kb + q1;
    const short* bsrc0 = BT + (size_t)(n0 + r0) * ldb + kb + q0;
    const short* bsrc1 = BT + (size_t)(n0 + r1) * ldb + kb + q1;

    f32x4 acc[4];
    for (int c = 0; c < 4; c++) acc[c] = (f32x4){0.f, 0.f, 0.f, 0.f};

    for (int kt = 0; kt < klen; kt += 64){
        __syncthreads();
        gl2lds16(asrc0 + kt, adst0);
        gl2lds16(asrc1 + kt, adst1);
        gl2lds16(bsrc0 + kt, bdst0);
        gl2lds16(bsrc1 + kt, bdst1);
        __syncthreads();
        int arow = w * 16 + l16;
        #pragma unroll
        for (int s = 0; s < 2; s++){
            short8 a = *(const short8*)(alds + arow * 64 + (((s * 4 + quad) ^ (l16 & 7)) * 8));
            #pragma unroll
            for (int c = 0; c < 4; c++){
                int brow = c * 16 + l16;
                short8 b = *(const short8*)(blds + brow * 64 + (((s * 4 + quad) ^ (l16 & 7)) * 8));
                acc[c] = __builtin_amdgcn_mfma_f32_16x16x32_bf16(a, b, acc[c], 0, 0, 0);
            }
        }
    }
    __syncthreads();   // protect LDS before reuse
    int mrow = m0 + w * 16 + quad * 4;
    #pragma unroll
    for (int c = 0; c < 4; c++){
        #pragma unroll
        for (int r = 0; r < 4; r++){
            size_t idx = (size_t)(mrow + r) * N + n0 + c * 16 + l16;
            if (mode == 2) ((short*)C)[idx] = f2bf(acc[c][r]);
            else ((float*)C)[idx] = acc[c][r];
        }
    }
}

__global__ __launch_bounds__(256, 2) void mega_kernel(Params p){
    int bid = blockIdx.x, t = threadIdx.x;
    __shared__ __align__(16) char smem[17024];

    // ================= phase 0: prep =================
    {
        int k = bid * 256 + t;
        if (bid < 8 && k < KP){
            const float* ss = p.size_scores + k * NSS;
            int psc = 0; float bs = ss[0];
            for (int s = 1; s < NSS; s++){ float v = ss[s]; if (v > bs){ bs = v; psc = s; } }
            for (int c = 0; c < 3; c++){
                float m = p.mean[psc * 3 + c];
                float r = p.srn[k * (NSS * 3) + psc * 3 + c];
                p.box[k * 3 + c] = m + r * m;
            }
            const float* cs = p.sem + k * NCC;
            double mx = (double)cs[0]; int lab = 0;
            for (int c = 1; c < NCC; c++){ double v = (double)cs[c]; if (v > mx){ mx = v; lab = c; } }
            double sum = 0.0;
            for (int c = 0; c < NCC; c++) sum += exp((double)cs[c] - mx);
            double prob = 1.0 / sum;
            p.probd[k] = prob;
            p.label[k] = lab;
            p.keyd[k]  = (lab > 0) ? prob : -1.0;
        }
    }
    gsync(p.arr, p.rel, 1, bid, t);

    // ================= phase 1: stable descending rank + scatter outputs =================
    {
        int* red = (int*)smem;
        const double2* k2 = (const double2*)p.keyd;
        for (int i = bid; i < KP; i += NBLK){
            double ki = p.keyd[i];
            int r = 0;
            #pragma unroll
            for (int pp = 0; pp < KP / 2 / 256; pp++){
                int idx2 = pp * 256 + t;
                double2 kj = k2[idx2];
                int j0 = idx2 * 2;
                r += (int)(kj.x > ki) + (int)((kj.x == ki) & (j0 < i));
                r += (int)(kj.y > ki) + (int)((kj.y == ki) & (j0 + 1 < i));
            }
            #pragma unroll
            for (int off = 32; off > 0; off >>= 1) r += __shfl_down(r, off);
            if ((t & 63) == 0) red[t >> 6] = r;
            __syncthreads();
            if (t == 0){
                int rk = red[0] + red[1] + red[2] + red[3];
                p.order[rk] = i;
                p.sprob[rk] = (p.label[i] > 0) ? (float)p.probd[i] : 0.f;
                p.out[KP + rk] = (float)(p.label[i] - 1);
                p.out[2 * KP + 3 * rk + 0] = p.box[i * 3 + 0];
                p.out[2 * KP + 3 * rk + 1] = p.box[i * 3 + 1];
                p.out[2 * KP + 3 * rk + 2] = p.box[i * 3 + 2];
            }
            __syncthreads();
        }
    }
    gsync(p.arr, p.rel, 2, bid, t);

    // ================= phase 2: af (emb | gathered features) + weight prep =================
    {
        for (int pos = bid; pos < KP; pos += NBLK){
            int ord = p.order[pos];
            float4 v = ((const float4*)(p.app + (size_t)ord * DD))[t];
            short4_t gg = { f2bf(v.x), f2bf(v.y), f2bf(v.z), f2bf(v.w) };
            *(short4_t*)(p.af + (size_t)pos * 2048 + 1024 + t * 4) = gg;
            short4_t e;
            #pragma unroll
            for (int i = 0; i < 4; i++){
                int j = t * 4 + i, jj = j & 511;
                float inv = exp2f(-(float)jj * 0.0194644224310197f);  // log2(1000)/512
                float arg = (float)pos * inv;
                e[i] = f2bf((j < 512) ? __sinf(arg) : __cosf(arg));
            }
            *(short4_t*)(p.af + (size_t)pos * 2048 + t * 4) = e;
        }
        int b = bid;
        if (b >= 128 && b < 192){   // u[h][f] = sum_e Wv[h][f][e]*wl[h*64+e]
            int i = b - 128;
            int h = i >> 2;
            int f = ((i & 3) << 8) + t;
            const float* wv = p.Wv + (size_t)h * DD * DKK + (size_t)f * DKK;
            const float* wlh = p.w_logit + h * DKK;
            float s = 0.f;
            #pragma unroll
            for (int e = 0; e < DKK; e++) s += wv[e] * wlh[e];
            p.uT[h * DD + f] = f2bf(s);
        } else if (b < 128){        // LDS-tiled transposes
            float (*tile)[65] = (float(*)[65])smem;
            const float* src; short* dst; int sstride, dstride, r0, c0, doff;
            float scale = 1.0f;
            if (b < 32){        src = p.w_rank; dst = p.wcat; sstride = DF; dstride = 2048;
                                r0 = (b >> 1) * 64; c0 = (b & 1) * 64; doff = 0; }
            else if (b < 64){   int i = b - 32; src = p.w_roi; dst = p.wcat; sstride = DF; dstride = 2048;
                                r0 = (i >> 1) * 64; c0 = (i & 1) * 64; doff = 1024; }
            else if (b < 96){   int i = b - 64; int h = i >> 1;
                                src = p.Wq + (size_t)h * DF * DKK; dst = p.qkT + (size_t)h * DKK * DF;
                                sstride = DKK; dstride = DF; r0 = (i & 1) * 64; c0 = 0; doff = 0;
                                scale = 0.125f; }   // fold 1/sqrt(dk) into q
            else {              int i = b - 96; int h = i >> 1;
                                src = p.Wk + (size_t)h * DF * DKK; dst = p.qkT + (size_t)(1024 + h * DKK) * DF;
                                sstride = DKK; dstride = DF; r0 = (i & 1) * 64; c0 = 0; doff = 0; }
            int tx = t & 63, ty = t >> 6;
            #pragma unroll
            for (int pp = 0; pp < 16; pp++){
                int r = pp * 4 + ty;
                tile[r][tx] = src[(size_t)(r0 + r) * sstride + c0 + tx];
            }
            __syncthreads();
            #pragma unroll
            for (int pp = 0; pp < 16; pp++){
                int r = pp * 4 + ty;
                dst[(size_t)(c0 + r) * dstride + doff + r0 + tx] = f2bf(tile[tx][r] * scale);
            }
        }
    }
    gsync(p.arr, p.rel, 3, bid, t);

    // ================= phase 3: e-GEMM  es[z] = af @ wcat^T  (K=2048, split-K=16) =================
    {
        #pragma unroll
        for (int it = 0; it < 2; it++){
            int vb = bid + it * NBLK;
            int m0 = (vb & 31) * 64, n0 = ((vb >> 5) & 1) * 64, z = vb >> 6;
            gemm_tile(p.af, p.wcat, p.es + (size_t)z * KP * DF,
                      2048, 2048, DF, 2048 / SPLK, z * (2048 / SPLK), m0, n0, 0, smem, t);
        }
    }
    gsync(p.arr, p.rel, 4, bid, t);

    // ================= phase 4: combine e slabs (+biases -> bf16)  +  vw = sf @ u =================
    {
        if (bid < 256){
            int base = (bid * 256 + t) * 4;
            int n = base & (DF - 1);
            float4 s = *(const float4*)(p.es + base);
            #pragma unroll
            for (int c = 1; c < SPLK; c++){
                float4 tt = *(const float4*)(p.es + (size_t)c * KP * DF + base);
                s.x += tt.x; s.y += tt.y; s.z += tt.z; s.w += tt.w;
            }
            float4 br = *(const float4*)(p.b_rank + n);
            float4 bo = *(const float4*)(p.b_roi + n);
            short4_t o = { f2bf(s.x + br.x + bo.x), f2bf(s.y + br.y + bo.y),
                           f2bf(s.z + br.z + bo.z), f2bf(s.w + br.w + bo.w) };
            *(short4_t*)(p.e_bf + base) = o;
        } else if (bid < 256 + KP / 64){
            int vb = bid - 256;
            int w = t >> 6, lane = t & 63, quad = lane >> 4, l16 = lane & 15;
            int m0 = vb * 64 + w * 16;
            f32x4 acc = (f32x4){0.f, 0.f, 0.f, 0.f};
            const short* arow = p.af + (size_t)(m0 + l16) * 2048 + 1024 + quad * 8;
            const short* brow = p.uT + (size_t)l16 * DD + quad * 8;
            for (int k0 = 0; k0 < DD; k0 += 32){
                short8 a = *(const short8*)(arow + k0);
                short8 b = *(const short8*)(brow + k0);
                acc = __builtin_amdgcn_mfma_f32_16x16x32_bf16(a, b, acc, 0, 0, 0);
            }
            #pragma unroll
            for (int r = 0; r < 4; r++)
                p.vwT[(size_t)l16 * KP + m0 + quad * 4 + r] = acc[r];
        }
    }
    gsync(p.arr, p.rel, 5, bid, t);

    // ================= phase 5: qk-GEMM  [q|k] = e @ qkT^T (K=128, bf16 out) =================
    {
        #pragma unroll
        for (int it = 0; it < 2; it++){
            int vb = bid + it * NBLK;
            int m0 = (vb & 31) * 64, n0 = (vb >> 5) * 64;
            gemm_tile(p.e_bf, p.qkT, p.qk_bf, DF, DF, 2048, DF, 0, m0, n0, 2, smem, t);
        }
    }
    gsync(p.arr, p.rel, 6, bid, t);

    // ================= phase 6: attention (QK^T, exp, two weighted row-sums) =================
    {
        int w = t >> 6, lane = t & 63, quad = lane >> 4, l16 = lane & 15;
        short* klds = (short*)smem;
        int seg0 = w * 128 + lane;
        int row0 = seg0 >> 3, c80 = (seg0 & 7) ^ (row0 & 7);
        int seg1 = seg0 + 64;
        int row1 = seg1 >> 3, c81 = (seg1 & 7) ^ (row1 & 7);
        short* kl0 = klds + (size_t)(w * 128) * 8;
        short* kl1 = klds + (size_t)(w * 128 + 64) * 8;

        #pragma unroll
        for (int it = 0; it < 2; it++){
            int job = bid + it * NBLK;
            int qt = job & 15, h = (job >> 4) & 15, ch = job >> 8;
            int qb = qt * 128;

            short8 aq[2][2];
            #pragma unroll
            for (int tt = 0; tt < 2; tt++){
                const short* qrow = p.qk_bf + (size_t)(qb + tt * 64 + w * 16 + l16) * 2048 + h * DKK;
                aq[tt][0] = *(const short8*)(qrow + quad * 8);
                aq[tt][1] = *(const short8*)(qrow + 32 + quad * 8);
            }
            float lpart[2][4] = {{0.f,0.f,0.f,0.f},{0.f,0.f,0.f,0.f}};
            float wpart[2][4] = {{0.f,0.f,0.f,0.f},{0.f,0.f,0.f,0.f}};

            for (int m0 = ch * CHUNK; m0 < (ch + 1) * CHUNK; m0 += 64){
                __syncthreads();
                gl2lds16(p.qk_bf + (size_t)(m0 + row0) * 2048 + 1024 + h * DKK + c80 * 8, kl0);
                gl2lds16(p.qk_bf + (size_t)(m0 + row1) * 2048 + 1024 + h * DKK + c81 * 8, kl1);
                float vwv[4];
                #pragma unroll
                for (int c = 0; c < 4; c++)
                    vwv[c] = p.vwT[(size_t)h * KP + m0 + c * 16 + l16];
                __syncthreads();

                #pragma unroll
                for (int tt = 0; tt < 2; tt++){
                    #pragma unroll
                    for (int c = 0; c < 4; c++){
                        int r = c * 16 + l16, sw = r & 7;
                        short8 b0 = *(const short8*)(klds + r * 64 + (quad ^ sw) * 8);
                        short8 b1 = *(const short8*)(klds + r * 64 + ((quad + 4) ^ sw) * 8);
                        f32x4 acc = (f32x4){0.f, 0.f, 0.f, 0.f};
                        acc = __builtin_amdgcn_mfma_f32_16x16x32_bf16(aq[tt][0], b0, acc, 0, 0, 0);
                        acc = __builtin_amdgcn_mfma_f32_16x16x32_bf16(aq[tt][1], b1, acc, 0, 0, 0);
                        #pragma unroll
                        for (int rr = 0; rr < 4; rr++){
                            float e = __expf(acc[rr]);
                            lpart[tt][rr] += e;
                            wpart[tt][rr] += e * vwv[c];
                        }
                    }
                }
            }
            __syncthreads();
            #pragma unroll
            for (int tt = 0; tt < 2; tt++){
                #pragma unroll
                for (int rr = 0; rr < 4; rr++){
                    float v = lpart[tt][rr], x = wpart[tt][rr];
                    v += __shfl_xor(v, 1); x += __shfl_xor(x, 1);
                    v += __shfl_xor(v, 2); x += __shfl_xor(x, 2);
                    v += __shfl_xor(v, 4); x += __shfl_xor(x, 4);
                    v += __shfl_xor(v, 8); x += __shfl_xor(x, 8);
                    lpart[tt][rr] = v; wpart[tt][rr] = x;
                }
                if (l16 == 0){
                    int qr0 = qb + tt * 64 + w * 16;
                    #pragma unroll
                    for (int rr = 0; rr < 4; rr++){
                        size_t idx = ((size_t)ch * NH + h) * KP + qr0 + quad * 4 + rr;
                        p.pl[idx]  = lpart[tt][rr];
                        p.pwl[idx] = wpart[tt][rr];
                    }
                }
            }
        }
    }
    gsync(p.arr, p.rel, 7, bid, t);

    // ================= phase 7: final logit + score =================
    {
        float* red = (float*)smem;
        float* hsum = red + 4;
        for (int pos = bid; pos < KP; pos += NBLK){
            int ord = p.order[pos];
            float4 a = *(const float4*)(p.app + (size_t)ord * DD + t * 4);
            float4 wv = *(const float4*)(p.w_logit + t * 4);
            float partial = a.x * wv.x + a.y * wv.y + a.z * wv.z + a.w * wv.w;
            for (int off = 32; off > 0; off >>= 1) partial += __shfl_down(partial, off);
            if ((t & 63) == 0) red[t >> 6] = partial;
            if (t < NH){
                float l = 0.f, x = 0.f;
                #pragma unroll
                for (int c = 0; c < NCH; c++){
                    size_t idx = ((size_t)c * NH + t) * KP + pos;
                    l += p.pl[idx]; x += p.pwl[idx];
                }
                hsum[t] = x / l;
            }
            __syncthreads();
            if (t == 0){
                float logit = red[0] + red[1] + red[2] + red[3] + p.b_logit[0];
                #pragma unroll
                for (int h = 0; h < NH; h++) logit += hsum[h];
                float s1 = 1.f / (1.f + __expf(-logit));
                p.out[pos] = s1 * p.sprob[pos];
            }
            __syncthreads();
        }
    }
}

extern "C" void kernel_launch(void* const* d_in, const int* in_sizes, int n_in,
                              void* d_out, int out_size, void* d_ws, size_t ws_size,
                              hipStream_t stream){
    (void)in_sizes; (void)n_in; (void)out_size; (void)ws_size;
    char* ws = (char*)d_ws;
    size_t off = 0;
    auto alloc = [&](size_t n) -> char* {
        char* pp = ws + off;
        off = (off + n + 255) & ~(size_t)255;
        return pp;
    };
    Params p;
    p.size_scores = (const float*)d_in[0];
    p.srn     = (const float*)d_in[1];
    p.sem     = (const float*)d_in[2];
    p.app     = (const float*)d_in[3];
    p.mean    = (const float*)d_in[4];
    p.w_rank  = (const float*)d_in[5];
    p.b_rank  = (const float*)d_in[6];
    p.w_roi   = (const float*)d_in[7];
    p.b_roi   = (const float*)d_in[8];
    p.Wq      = (const float*)d_in[9];
    p.Wk      = (const float*)d_in[10];
    p.Wv      = (const float*)d_in[11];
    p.w_logit = (const float*)d_in[12];
    p.b_logit = (const float*)d_in[13];
    p.out     = (float*)d_out;
    p.arr    = (unsigned*) alloc((size_t)NBLK * 4);
    p.rel    = (unsigned*) alloc((size_t)NBLK * 4);
    p.box    = (float*) alloc((size_t)KP * 3 * 4);
    p.label  = (int*)   alloc((size_t)KP * 4);
    p.probd  = (double*)alloc((size_t)KP * 8);
    p.keyd   = (double*)alloc((size_t)KP * 8);
    p.order  = (int*)   alloc((size_t)KP * 4);
    p.sprob  = (float*) alloc((size_t)KP * 4);
    p.wcat   = (short*) alloc((size_t)DF * 2048 * 2);
    p.qkT    = (short*) alloc((size_t)2048 * DF * 2);
    p.uT     = (short*) alloc((size_t)NH * DD * 2);
    p.e_bf   = (short*) alloc((size_t)KP * DF * 2);
    p.qk_bf  = (short*) alloc((size_t)KP * 2048 * 2);
    p.vwT    = (float*) alloc((size_t)NH * KP * 4);
    p.pl     = (float*) alloc((size_t)NCH * NH * KP * 4);
    p.pwl    = (float*) alloc((size_t)NCH * NH * KP * 4);
    p.af     = (short*) alloc((size_t)KP * 2048 * 2);
    p.es     = (float*) alloc((size_t)SPLK * KP * DF * 4);

    hipMemsetAsync(p.arr, 0, (size_t)NBLK * 4 * 2, stream);   // zero arr+rel (contiguous)
    mega_kernel<<<NBLK, 256, 0, stream>>>(p);
}

// Round 11
// 154.265 us; speedup vs baseline: 4.8194x; 3.0296x over previous
//
#include <hip/hip_runtime.h>

#define KP 2048
#define DD 1024
#define DF 128
#define NH 16
#define DKK 64
#define NSS 18
#define NCC 19
#define NCH 2
#define CHUNK 1024
#define SPLK 16

typedef __attribute__((ext_vector_type(8))) short short8;
typedef __attribute__((ext_vector_type(4))) short short4_t;
typedef __attribute__((ext_vector_type(4))) float f32x4;

__device__ __forceinline__ short f2bf(float x){
    unsigned u = __float_as_uint(x);
    u += 0x7fffu + ((u >> 16) & 1u);   // round-to-nearest-even
    return (short)(u >> 16);
}

__device__ __forceinline__ void gl2lds16(const void* g, void* l){
    __builtin_amdgcn_global_load_lds((const __attribute__((address_space(1))) void*)g,
                                     (__attribute__((address_space(3))) void*)l, 16, 0, 0);
}

// ---------------- dispatch 1: prep (blocks 0..7) + weight prep (blocks 8..199) ----------------
__global__ __launch_bounds__(256) void prep_convw_kernel(const float* __restrict__ size_scores,
        const float* __restrict__ srn, const float* __restrict__ sem,
        const float* __restrict__ mean,
        const float* __restrict__ w_rank, const float* __restrict__ w_roi,
        const float* __restrict__ Wq, const float* __restrict__ Wk,
        const float* __restrict__ Wv, const float* __restrict__ w_logit,
        float* __restrict__ box, int* __restrict__ label,
        double* __restrict__ probd, double* __restrict__ keyd,
        short* __restrict__ wcat, short* __restrict__ qkT, short* __restrict__ uT){
    int bid = blockIdx.x, t = threadIdx.x;
    if (bid < 8){
        int k = bid * 256 + t;
        const float* ss = size_scores + k * NSS;
        int psc = 0; float bs = ss[0];
        for (int s = 1; s < NSS; s++){ float v = ss[s]; if (v > bs){ bs = v; psc = s; } }
        for (int c = 0; c < 3; c++){
            float m = mean[psc * 3 + c];
            float r = srn[k * (NSS * 3) + psc * 3 + c];
            box[k * 3 + c] = m + r * m;
        }
        const float* cs = sem + k * NCC;
        double mx = (double)cs[0]; int lab = 0;
        for (int c = 1; c < NCC; c++){ double v = (double)cs[c]; if (v > mx){ mx = v; lab = c; } }
        double sum = 0.0;
        for (int c = 0; c < NCC; c++) sum += exp((double)cs[c] - mx);
        probd[k] = 1.0 / sum;
        label[k] = lab;
        keyd[k]  = (lab > 0) ? (1.0 / sum) : -1.0;
        return;
    }
    int b = bid - 8;
    if (b >= 128){   // u[h][f] = sum_e Wv[h][f][e] * wl[h*64+e]
        int i = b - 128;
        int h = i >> 2;
        int f = ((i & 3) << 8) + t;
        const float* wv = Wv + (size_t)h * DD * DKK + (size_t)f * DKK;
        const float* wlh = w_logit + h * DKK;
        float s = 0.f;
        #pragma unroll
        for (int e = 0; e < DKK; e++) s += wv[e] * wlh[e];
        uT[h * DD + f] = f2bf(s);
        return;
    }
    __shared__ float tile[64][65];
    const float* src; short* dst; int sstride, dstride, r0, c0, doff;
    float scale = 1.0f;
    if (b < 32){        src = w_rank; dst = wcat; sstride = DF; dstride = 2048;
                        r0 = (b >> 1) * 64; c0 = (b & 1) * 64; doff = 0; }
    else if (b < 64){   int i = b - 32; src = w_roi; dst = wcat; sstride = DF; dstride = 2048;
                        r0 = (i >> 1) * 64; c0 = (i & 1) * 64; doff = 1024; }
    else if (b < 96){   int i = b - 64; int h = i >> 1;
                        src = Wq + (size_t)h * DF * DKK; dst = qkT + (size_t)h * DKK * DF;
                        sstride = DKK; dstride = DF; r0 = (i & 1) * 64; c0 = 0; doff = 0;
                        scale = 0.125f; }   // fold 1/sqrt(dk) into q
    else {              int i = b - 96; int h = i >> 1;
                        src = Wk + (size_t)h * DF * DKK; dst = qkT + (size_t)(1024 + h * DKK) * DF;
                        sstride = DKK; dstride = DF; r0 = (i & 1) * 64; c0 = 0; doff = 0; }
    int tx = t & 63, ty = t >> 6;
    #pragma unroll
    for (int pp = 0; pp < 16; pp++){
        int r = pp * 4 + ty;
        tile[r][tx] = src[(size_t)(r0 + r) * sstride + c0 + tx];
    }
    __syncthreads();
    #pragma unroll
    for (int pp = 0; pp < 16; pp++){
        int r = pp * 4 + ty;
        dst[(size_t)(c0 + r) * dstride + doff + r0 + tx] = f2bf(tile[tx][r] * scale);
    }
}

// ---------------- dispatch 2: rank + af fill + dotl + outputs 1,2 + counter zero ----------------
// block i computes its stable-descending rank rk, then directly fills af[rk] (gather from
// app[i], coalesced) and dotl[rk] = app[i].w_logit (fused into the gather loads).
__global__ __launch_bounds__(256) void rank_af_kernel(const double* __restrict__ keyd,
        const int* __restrict__ label, const double* __restrict__ probd,
        const float* __restrict__ box, const float* __restrict__ app,
        const float* __restrict__ w_logit,
        int* __restrict__ order, float* __restrict__ sprob, float* __restrict__ dotl,
        short* __restrict__ af, unsigned* __restrict__ cnt, float* __restrict__ out){
    int i = blockIdx.x, t = threadIdx.x;
    if (i < 16 && t == 0) cnt[i] = 0;   // attn completion counters (3 dispatches later)
    __shared__ int redi[4];
    __shared__ float redf[4];
    __shared__ int rks;
    double ki = keyd[i];
    const double2* k2 = (const double2*)keyd;
    int r = 0;
    #pragma unroll
    for (int pp = 0; pp < KP / 2 / 256; pp++){
        int idx2 = pp * 256 + t;
        double2 kj = k2[idx2];
        int j0 = idx2 * 2;
        r += (int)(kj.x > ki) + (int)((kj.x == ki) & (j0 < i));
        r += (int)(kj.y > ki) + (int)((kj.y == ki) & (j0 + 1 < i));
    }
    #pragma unroll
    for (int off = 32; off > 0; off >>= 1) r += __shfl_down(r, off);
    if ((t & 63) == 0) redi[t >> 6] = r;
    __syncthreads();
    if (t == 0){
        int rk = redi[0] + redi[1] + redi[2] + redi[3];
        rks = rk;
        order[rk] = i;
        sprob[rk] = (label[i] > 0) ? (float)probd[i] : 0.f;
        out[KP + rk] = (float)(label[i] - 1);
        out[2 * KP + 3 * rk + 0] = box[i * 3 + 0];
        out[2 * KP + 3 * rk + 1] = box[i * 3 + 1];
        out[2 * KP + 3 * rk + 2] = box[i * 3 + 2];
    }
    __syncthreads();
    int pos = rks;
    // gather + logit-dot (sorted features -> af cols 1024:2048)
    float4 v = ((const float4*)(app + (size_t)i * DD))[t];
    float4 wv = ((const float4*)w_logit)[t];
    short4_t gg = { f2bf(v.x), f2bf(v.y), f2bf(v.z), f2bf(v.w) };
    *(short4_t*)(af + (size_t)pos * 2048 + 1024 + t * 4) = gg;
    float partial = v.x * wv.x + v.y * wv.y + v.z * wv.z + v.w * wv.w;
    #pragma unroll
    for (int off = 32; off > 0; off >>= 1) partial += __shfl_down(partial, off);
    if ((t & 63) == 0) redf[t >> 6] = partial;
    // rank (positional) embedding -> af cols 0:1024
    short4_t e;
    #pragma unroll
    for (int ii = 0; ii < 4; ii++){
        int j = t * 4 + ii, jj = j & 511;
        float inv = exp2f(-(float)jj * 0.0194644224310197f);  // log2(1000)/512
        float arg = (float)pos * inv;
        e[ii] = f2bf((j < 512) ? __sinf(arg) : __cosf(arg));
    }
    *(short4_t*)(af + (size_t)pos * 2048 + t * 4) = e;
    __syncthreads();
    if (t == 0) dotl[pos] = redf[0] + redf[1] + redf[2] + redf[3];
}

// ---------------- LDS-staged bf16 GEMM: 64x64 tile, BK=64, optional split-K slabs ----------------
__global__ __launch_bounds__(256) void gemm_lds(const short* __restrict__ A,
                                                const short* __restrict__ BT,
                                                void* __restrict__ C,
                                                int lda, int ldb, int N,
                                                int klen, size_t slabstride, int mode){
    int w = threadIdx.x >> 6, lane = threadIdx.x & 63;
    int quad = lane >> 4, l16 = lane & 15;
    int m0 = blockIdx.x * 64, n0 = blockIdx.y * 64;
    int kb = blockIdx.z * klen;

    __shared__ __align__(16) short alds[64 * 64];
    __shared__ __align__(16) short blds[64 * 64];

    int p0 = w * 64 + lane;
    int r0 = p0 >> 3, q0 = ((p0 & 7) ^ (r0 & 7)) * 8;
    int p1 = p0 + 256;
    int r1 = p1 >> 3, q1 = ((p1 & 7) ^ (r1 & 7)) * 8;
    short* adst0 = alds + w * 512;
    short* adst1 = alds + 2048 + w * 512;
    short* bdst0 = blds + w * 512;
    short* bdst1 = blds + 2048 + w * 512;
    const short* asrc0 = A + (size_t)(m0 + r0) * lda + kb + q0;
    const short* asrc1 = A + (size_t)(m0 + r1) * lda + kb + q1;
    const short* bsrc0 = BT + (size_t)(n0 + r0) * ldb + kb + q0;
    const short* bsrc1 = BT + (size_t)(n0 + r1) * ldb + kb + q1;

    f32x4 acc[4];
    for (int c = 0; c < 4; c++) acc[c] = (f32x4){0.f, 0.f, 0.f, 0.f};

    for (int kt = 0; kt < klen; kt += 64){
        __syncthreads();
        gl2lds16(asrc0 + kt, adst0);
        gl2lds16(asrc1 + kt, adst1);
        gl2lds16(bsrc0 + kt, bdst0);
        gl2lds16(bsrc1 + kt, bdst1);
        __syncthreads();
        int arow = w * 16 + l16;
        #pragma unroll
        for (int s = 0; s < 2; s++){
            short8 a = *(const short8*)(alds + arow * 64 + (((s * 4 + quad) ^ (l16 & 7)) * 8));
            #pragma unroll
            for (int c = 0; c < 4; c++){
                int brow = c * 16 + l16;
                short8 b = *(const short8*)(blds + brow * 64 + (((s * 4 + quad) ^ (l16 & 7)) * 8));
                acc[c] = __builtin_amdgcn_mfma_f32_16x16x32_bf16(a, b, acc[c], 0, 0, 0);
            }
        }
    }
    int mrow = m0 + w * 16 + quad * 4;
    #pragma unroll
    for (int c = 0; c < 4; c++){
        #pragma unroll
        for (int r = 0; r < 4; r++){
            size_t idx = (size_t)(mrow + r) * N + n0 + c * 16 + l16;
            if (mode == 2) ((short*)C)[idx] = f2bf(acc[c][r]);
            else ((float*)C + (size_t)blockIdx.z * slabstride)[idx] = acc[c][r];
        }
    }
}

// ---------------- dispatch 4: combine e slabs (+biases -> bf16) + vw = sf @ u ----------------
__global__ __launch_bounds__(256) void comb_vw_kernel(const float* __restrict__ es,
        const float* __restrict__ b_rank, const float* __restrict__ b_roi,
        const short* __restrict__ af, const short* __restrict__ uT,
        short* __restrict__ e_bf, float* __restrict__ vwT){
    int bid = blockIdx.x, t = threadIdx.x;
    if (bid < 256){
        int base = (bid * 256 + t) * 4;
        int n = base & (DF - 1);
        float4 s = *(const float4*)(es + base);
        #pragma unroll
        for (int c = 1; c < SPLK; c++){
            float4 tt = *(const float4*)(es + (size_t)c * KP * DF + base);
            s.x += tt.x; s.y += tt.y; s.z += tt.z; s.w += tt.w;
        }
        float4 br = *(const float4*)(b_rank + n);
        float4 bo = *(const float4*)(b_roi + n);
        short4_t o = { f2bf(s.x + br.x + bo.x), f2bf(s.y + br.y + bo.y),
                       f2bf(s.z + br.z + bo.z), f2bf(s.w + br.w + bo.w) };
        *(short4_t*)(e_bf + base) = o;
    } else {
        int vb = bid - 256;
        int w = t >> 6, lane = t & 63, quad = lane >> 4, l16 = lane & 15;
        int m0 = vb * 64 + w * 16;
        f32x4 acc = (f32x4){0.f, 0.f, 0.f, 0.f};
        const short* arow = af + (size_t)(m0 + l16) * 2048 + 1024 + quad * 8;
        const short* brow = uT + (size_t)l16 * DD + quad * 8;
        for (int k0 = 0; k0 < DD; k0 += 32){
            short8 a = *(const short8*)(arow + k0);
            short8 b = *(const short8*)(brow + k0);
            acc = __builtin_amdgcn_mfma_f32_16x16x32_bf16(a, b, acc, 0, 0, 0);
        }
        #pragma unroll
        for (int r = 0; r < 4; r++)
            vwT[(size_t)l16 * KP + m0 + quad * 4 + r] = acc[r];
    }
}

// ---------------- dispatch 6: attention + last-block final ----------------
// grid (16 qt, 16 h, 2 ch). Publishes pl/pwl partials via device-scope atomic stores;
// last of 32 blocks per qt computes the 128 final scores.
__global__ __launch_bounds__(256, 4) void attn_final_kernel(const short* __restrict__ qk,
        const float* __restrict__ vwT, const float* __restrict__ dotl,
        const float* __restrict__ sprob, const float* __restrict__ b_logit,
        float* __restrict__ pl, float* __restrict__ pwl,
        unsigned* __restrict__ cnt, float* __restrict__ out){
    int qt = blockIdx.x, h = blockIdx.y, ch = blockIdx.z;
    int t = threadIdx.x;
    int w = t >> 6, lane = t & 63, quad = lane >> 4, l16 = lane & 15;
    int qb = qt * 128;

    __shared__ __align__(16) short klds[64 * 64];
    __shared__ int lastf;

    short8 aq[2][2];
    #pragma unroll
    for (int tt = 0; tt < 2; tt++){
        const short* qrow = qk + (size_t)(qb + tt * 64 + w * 16 + l16) * 2048 + h * DKK;
        aq[tt][0] = *(const short8*)(qrow + quad * 8);
        aq[tt][1] = *(const short8*)(qrow + 32 + quad * 8);
    }
    float lpart[2][4] = {{0.f,0.f,0.f,0.f},{0.f,0.f,0.f,0.f}};
    float wpart[2][4] = {{0.f,0.f,0.f,0.f},{0.f,0.f,0.f,0.f}};

    int seg0 = w * 128 + lane;
    int row0 = seg0 >> 3, c80 = (seg0 & 7) ^ (row0 & 7);
    int seg1 = seg0 + 64;
    int row1 = seg1 >> 3, c81 = (seg1 & 7) ^ (row1 & 7);
    short* kl0 = klds + (size_t)(w * 128) * 8;
    short* kl1 = klds + (size_t)(w * 128 + 64) * 8;

    for (int m0 = ch * CHUNK; m0 < (ch + 1) * CHUNK; m0 += 64){
        __syncthreads();
        gl2lds16(qk + (size_t)(m0 + row0) * 2048 + 1024 + h * DKK + c80 * 8, kl0);
        gl2lds16(qk + (size_t)(m0 + row1) * 2048 + 1024 + h * DKK + c81 * 8, kl1);
        float vwv[4];
        #pragma unroll
        for (int c = 0; c < 4; c++)
            vwv[c] = vwT[(size_t)h * KP + m0 + c * 16 + l16];
        __syncthreads();

        #pragma unroll
        for (int tt = 0; tt < 2; tt++){
            #pragma unroll
            for (int c = 0; c < 4; c++){
                int r = c * 16 + l16, sw = r & 7;
                short8 b0 = *(const short8*)(klds + r * 64 + (quad ^ sw) * 8);
                short8 b1 = *(const short8*)(klds + r * 64 + ((quad + 4) ^ sw) * 8);
                f32x4 acc = (f32x4){0.f, 0.f, 0.f, 0.f};
                acc = __builtin_amdgcn_mfma_f32_16x16x32_bf16(aq[tt][0], b0, acc, 0, 0, 0);
                acc = __builtin_amdgcn_mfma_f32_16x16x32_bf16(aq[tt][1], b1, acc, 0, 0, 0);
                #pragma unroll
                for (int rr = 0; rr < 4; rr++){
                    float e = __expf(acc[rr]);
                    lpart[tt][rr] += e;
                    wpart[tt][rr] += e * vwv[c];
                }
            }
        }
    }

    #pragma unroll
    for (int tt = 0; tt < 2; tt++){
        #pragma unroll
        for (int rr = 0; rr < 4; rr++){
            float v = lpart[tt][rr], x = wpart[tt][rr];
            v += __shfl_xor(v, 1); x += __shfl_xor(x, 1);
            v += __shfl_xor(v, 2); x += __shfl_xor(x, 2);
            v += __shfl_xor(v, 4); x += __shfl_xor(x, 4);
            v += __shfl_xor(v, 8); x += __shfl_xor(x, 8);
            lpart[tt][rr] = v; wpart[tt][rr] = x;
        }
        if (l16 == 0){
            int qr0 = qb + tt * 64 + w * 16;
            #pragma unroll
            for (int rr = 0; rr < 4; rr++){
                size_t idx = ((size_t)ch * NH + h) * KP + qr0 + quad * 4 + rr;
                __hip_atomic_store(pl + idx,  lpart[tt][rr], __ATOMIC_RELAXED, __HIP_MEMORY_SCOPE_AGENT);
                __hip_atomic_store(pwl + idx, wpart[tt][rr], __ATOMIC_RELAXED, __HIP_MEMORY_SCOPE_AGENT);
            }
        }
    }
    // completion protocol: last of 32 blocks (16 h x 2 ch) for this qt does the epilogue
    __syncthreads();
    if (t == 0){
        __threadfence();
        unsigned old = __hip_atomic_fetch_add(cnt + qt, 1u, __ATOMIC_ACQ_REL, __HIP_MEMORY_SCOPE_AGENT);
        lastf = (old == 31);
    }
    __syncthreads();
    if (lastf){
        __threadfence();
        if (t < 128){
            int pos = qb + t;
            float logit = dotl[pos] + b_logit[0];
            #pragma unroll
            for (int hh = 0; hh < NH; hh++){
                size_t i0 = ((size_t)0 * NH + hh) * KP + pos;
                size_t i1 = ((size_t)1 * NH + hh) * KP + pos;
                float l = __hip_atomic_load(pl + i0, __ATOMIC_RELAXED, __HIP_MEMORY_SCOPE_AGENT)
                        + __hip_atomic_load(pl + i1, __ATOMIC_RELAXED, __HIP_MEMORY_SCOPE_AGENT);
                float x = __hip_atomic_load(pwl + i0, __ATOMIC_RELAXED, __HIP_MEMORY_SCOPE_AGENT)
                        + __hip_atomic_load(pwl + i1, __ATOMIC_RELAXED, __HIP_MEMORY_SCOPE_AGENT);
                logit += x / l;
            }
            float s1 = 1.f / (1.f + __expf(-logit));
            out[pos] = s1 * sprob[pos];
        }
    }
}

extern "C" void kernel_launch(void* const* d_in, const int* in_sizes, int n_in,
                              void* d_out, int out_size, void* d_ws, size_t ws_size,
                              hipStream_t stream){
    (void)in_sizes; (void)n_in; (void)out_size; (void)ws_size;
    const float* size_scores = (const float*)d_in[0];
    const float* srn     = (const float*)d_in[1];
    const float* sem     = (const float*)d_in[2];
    const float* app     = (const float*)d_in[3];
    const float* mean    = (const float*)d_in[4];
    const float* w_rank  = (const float*)d_in[5];
    const float* b_rank  = (const float*)d_in[6];
    const float* w_roi   = (const float*)d_in[7];
    const float* b_roi   = (const float*)d_in[8];
    const float* Wq      = (const float*)d_in[9];
    const float* Wk      = (const float*)d_in[10];
    const float* Wv      = (const float*)d_in[11];
    const float* w_logit = (const float*)d_in[12];
    const float* b_logit = (const float*)d_in[13];
    float* out = (float*)d_out;

    char* ws = (char*)d_ws;
    size_t off = 0;
    auto alloc = [&](size_t n) -> char* {
        char* pp = ws + off;
        off = (off + n + 255) & ~(size_t)255;
        return pp;
    };
    float*    box   = (float*)   alloc((size_t)KP * 3 * 4);
    int*      label = (int*)     alloc((size_t)KP * 4);
    double*   probd = (double*)  alloc((size_t)KP * 8);
    double*   keyd  = (double*)  alloc((size_t)KP * 8);
    int*      order = (int*)     alloc((size_t)KP * 4);
    float*    sprob = (float*)   alloc((size_t)KP * 4);
    float*    dotl  = (float*)   alloc((size_t)KP * 4);
    unsigned* cnt   = (unsigned*)alloc(16 * 4);
    short*    wcat  = (short*)   alloc((size_t)DF * 2048 * 2);
    short*    qkT   = (short*)   alloc((size_t)2048 * DF * 2);
    short*    uT    = (short*)   alloc((size_t)NH * DD * 2);
    short*    e_bf  = (short*)   alloc((size_t)KP * DF * 2);
    short*    qk_bf = (short*)   alloc((size_t)KP * 2048 * 2);
    float*    vwT   = (float*)   alloc((size_t)NH * KP * 4);
    float*    pl    = (float*)   alloc((size_t)NCH * NH * KP * 4);
    float*    pwl   = (float*)   alloc((size_t)NCH * NH * KP * 4);
    short*    af    = (short*)   alloc((size_t)KP * 2048 * 2);
    float*    es    = (float*)   alloc((size_t)SPLK * KP * DF * 4);

    prep_convw_kernel<<<200, 256, 0, stream>>>(size_scores, srn, sem, mean,
        w_rank, w_roi, Wq, Wk, Wv, w_logit, box, label, probd, keyd, wcat, qkT, uT);
    rank_af_kernel<<<KP, 256, 0, stream>>>(keyd, label, probd, box, app, w_logit,
        order, sprob, dotl, af, cnt, out);
    gemm_lds<<<dim3(32, 2, SPLK), 256, 0, stream>>>(af, wcat, es, 2048, 2048, DF,
        2048 / SPLK, (size_t)KP * DF, 0);
    comb_vw_kernel<<<288, 256, 0, stream>>>(es, b_rank, b_roi, af, uT, e_bf, vwT);
    gemm_lds<<<dim3(32, 32, 1), 256, 0, stream>>>(e_bf, qkT, qk_bf, DF, DF, 2048, DF, 0, 2);
    attn_final_kernel<<<dim3(16, NH, NCH), 256, 0, stream>>>(qk_bf, vwT, dotl, sprob,
        b_logit, pl, pwl, cnt, out);
}

// Round 12
// 139.926 us; speedup vs baseline: 5.3133x; 1.1025x over previous
//
#include <hip/hip_runtime.h>

#define KP 2048
#define DD 1024
#define DF 128
#define NH 16
#define DKK 64
#define NSS 18
#define NCC 19
#define NCH 4
#define CHUNK 512
#define SPLK 8

typedef __attribute__((ext_vector_type(8))) short short8;
typedef __attribute__((ext_vector_type(4))) short short4_t;
typedef __attribute__((ext_vector_type(4))) float f32x4;

__device__ __forceinline__ short f2bf(float x){
    unsigned u = __float_as_uint(x);
    u += 0x7fffu + ((u >> 16) & 1u);   // round-to-nearest-even
    return (short)(u >> 16);
}

__device__ __forceinline__ void gl2lds16(const void* g, void* l){
    __builtin_amdgcn_global_load_lds((const __attribute__((address_space(1))) void*)g,
                                     (__attribute__((address_space(3))) void*)l, 16, 0, 0);
}

// ---------------- dispatch 1: prep (blocks 0..7) + weight prep (blocks 8..199) ----------------
__global__ __launch_bounds__(256) void prep_convw_kernel(const float* __restrict__ size_scores,
        const float* __restrict__ srn, const float* __restrict__ sem,
        const float* __restrict__ mean,
        const float* __restrict__ w_rank, const float* __restrict__ w_roi,
        const float* __restrict__ Wq, const float* __restrict__ Wk,
        const float* __restrict__ Wv, const float* __restrict__ w_logit,
        float* __restrict__ box, int* __restrict__ label,
        double* __restrict__ probd, double* __restrict__ keyd,
        short* __restrict__ wcat, short* __restrict__ qkT, short* __restrict__ uT){
    int bid = blockIdx.x, t = threadIdx.x;
    if (bid < 8){
        int k = bid * 256 + t;
        const float* ss = size_scores + k * NSS;
        int psc = 0; float bs = ss[0];
        for (int s = 1; s < NSS; s++){ float v = ss[s]; if (v > bs){ bs = v; psc = s; } }
        for (int c = 0; c < 3; c++){
            float m = mean[psc * 3 + c];
            float r = srn[k * (NSS * 3) + psc * 3 + c];
            box[k * 3 + c] = m + r * m;
        }
        const float* cs = sem + k * NCC;
        double mx = (double)cs[0]; int lab = 0;
        for (int c = 1; c < NCC; c++){ double v = (double)cs[c]; if (v > mx){ mx = v; lab = c; } }
        double sum = 0.0;
        for (int c = 0; c < NCC; c++) sum += exp((double)cs[c] - mx);
        probd[k] = 1.0 / sum;
        label[k] = lab;
        keyd[k]  = (lab > 0) ? (1.0 / sum) : -1.0;
        return;
    }
    int b = bid - 8;
    if (b >= 128){   // u[h][f] = sum_e Wv[h][f][e] * wl[h*64+e]
        int i = b - 128;
        int h = i >> 2;
        int f = ((i & 3) << 8) + t;
        const float* wv = Wv + (size_t)h * DD * DKK + (size_t)f * DKK;
        const float* wlh = w_logit + h * DKK;
        float s = 0.f;
        #pragma unroll
        for (int e = 0; e < DKK; e++) s += wv[e] * wlh[e];
        uT[h * DD + f] = f2bf(s);
        return;
    }
    __shared__ float tile[64][65];
    const float* src; short* dst; int sstride, dstride, r0, c0, doff;
    float scale = 1.0f;
    if (b < 32){        src = w_rank; dst = wcat; sstride = DF; dstride = 2048;
                        r0 = (b >> 1) * 64; c0 = (b & 1) * 64; doff = 0; }
    else if (b < 64){   int i = b - 32; src = w_roi; dst = wcat; sstride = DF; dstride = 2048;
                        r0 = (i >> 1) * 64; c0 = (i & 1) * 64; doff = 1024; }
    else if (b < 96){   int i = b - 64; int h = i >> 1;
                        src = Wq + (size_t)h * DF * DKK; dst = qkT + (size_t)h * DKK * DF;
                        sstride = DKK; dstride = DF; r0 = (i & 1) * 64; c0 = 0; doff = 0;
                        scale = 0.125f; }   // fold 1/sqrt(dk) into q
    else {              int i = b - 96; int h = i >> 1;
                        src = Wk + (size_t)h * DF * DKK; dst = qkT + (size_t)(1024 + h * DKK) * DF;
                        sstride = DKK; dstride = DF; r0 = (i & 1) * 64; c0 = 0; doff = 0; }
    int tx = t & 63, ty = t >> 6;
    #pragma unroll
    for (int pp = 0; pp < 16; pp++){
        int r = pp * 4 + ty;
        tile[r][tx] = src[(size_t)(r0 + r) * sstride + c0 + tx];
    }
    __syncthreads();
    #pragma unroll
    for (int pp = 0; pp < 16; pp++){
        int r = pp * 4 + ty;
        dst[(size_t)(c0 + r) * dstride + doff + r0 + tx] = f2bf(tile[tx][r] * scale);
    }
}

// ---------------- dispatch 2: rank + af fill + dotl + outputs 1,2 ----------------
__global__ __launch_bounds__(256) void rank_af_kernel(const double* __restrict__ keyd,
        const int* __restrict__ label, const double* __restrict__ probd,
        const float* __restrict__ box, const float* __restrict__ app,
        const float* __restrict__ w_logit,
        float* __restrict__ sprob, float* __restrict__ dotl,
        short* __restrict__ af, float* __restrict__ out){
    int i = blockIdx.x, t = threadIdx.x;
    __shared__ int redi[4];
    __shared__ float redf[4];
    __shared__ int rks;
    double ki = keyd[i];
    const double2* k2 = (const double2*)keyd;
    int r = 0;
    #pragma unroll
    for (int pp = 0; pp < KP / 2 / 256; pp++){
        int idx2 = pp * 256 + t;
        double2 kj = k2[idx2];
        int j0 = idx2 * 2;
        r += (int)(kj.x > ki) + (int)((kj.x == ki) & (j0 < i));
        r += (int)(kj.y > ki) + (int)((kj.y == ki) & (j0 + 1 < i));
    }
    #pragma unroll
    for (int off = 32; off > 0; off >>= 1) r += __shfl_down(r, off);
    if ((t & 63) == 0) redi[t >> 6] = r;
    __syncthreads();
    if (t == 0){
        int rk = redi[0] + redi[1] + redi[2] + redi[3];
        rks = rk;
        sprob[rk] = (label[i] > 0) ? (float)probd[i] : 0.f;
        out[KP + rk] = (float)(label[i] - 1);
        out[2 * KP + 3 * rk + 0] = box[i * 3 + 0];
        out[2 * KP + 3 * rk + 1] = box[i * 3 + 1];
        out[2 * KP + 3 * rk + 2] = box[i * 3 + 2];
    }
    __syncthreads();
    int pos = rks;
    // gather + logit-dot (sorted features -> af cols 1024:2048)
    float4 v = ((const float4*)(app + (size_t)i * DD))[t];
    float4 wv = ((const float4*)w_logit)[t];
    short4_t gg = { f2bf(v.x), f2bf(v.y), f2bf(v.z), f2bf(v.w) };
    *(short4_t*)(af + (size_t)pos * 2048 + 1024 + t * 4) = gg;
    float partial = v.x * wv.x + v.y * wv.y + v.z * wv.z + v.w * wv.w;
    #pragma unroll
    for (int off = 32; off > 0; off >>= 1) partial += __shfl_down(partial, off);
    if ((t & 63) == 0) redf[t >> 6] = partial;
    // rank (positional) embedding -> af cols 0:1024
    short4_t e;
    #pragma unroll
    for (int ii = 0; ii < 4; ii++){
        int j = t * 4 + ii, jj = j & 511;
        float inv = exp2f(-(float)jj * 0.0194644224310197f);  // log2(1000)/512
        float arg = (float)pos * inv;
        e[ii] = f2bf((j < 512) ? __sinf(arg) : __cosf(arg));
    }
    *(short4_t*)(af + (size_t)pos * 2048 + t * 4) = e;
    __syncthreads();
    if (t == 0) dotl[pos] = redf[0] + redf[1] + redf[2] + redf[3];
}

// ---------------- LDS-staged bf16 GEMM: 64x64 tile, BK=64, optional split-K slabs ----------------
__global__ __launch_bounds__(256) void gemm_lds(const short* __restrict__ A,
                                                const short* __restrict__ BT,
                                                void* __restrict__ C,
                                                int lda, int ldb, int N,
                                                int klen, size_t slabstride, int mode){
    int w = threadIdx.x >> 6, lane = threadIdx.x & 63;
    int quad = lane >> 4, l16 = lane & 15;
    int m0 = blockIdx.x * 64, n0 = blockIdx.y * 64;
    int kb = blockIdx.z * klen;

    __shared__ __align__(16) short alds[64 * 64];
    __shared__ __align__(16) short blds[64 * 64];

    int p0 = w * 64 + lane;
    int r0 = p0 >> 3, q0 = ((p0 & 7) ^ (r0 & 7)) * 8;
    int p1 = p0 + 256;
    int r1 = p1 >> 3, q1 = ((p1 & 7) ^ (r1 & 7)) * 8;
    short* adst0 = alds + w * 512;
    short* adst1 = alds + 2048 + w * 512;
    short* bdst0 = blds + w * 512;
    short* bdst1 = blds + 2048 + w * 512;
    const short* asrc0 = A + (size_t)(m0 + r0) * lda + kb + q0;
    const short* asrc1 = A + (size_t)(m0 + r1) * lda + kb + q1;
    const short* bsrc0 = BT + (size_t)(n0 + r0) * ldb + kb + q0;
    const short* bsrc1 = BT + (size_t)(n0 + r1) * ldb + kb + q1;

    f32x4 acc[4];
    for (int c = 0; c < 4; c++) acc[c] = (f32x4){0.f, 0.f, 0.f, 0.f};

    for (int kt = 0; kt < klen; kt += 64){
        __syncthreads();
        gl2lds16(asrc0 + kt, adst0);
        gl2lds16(asrc1 + kt, adst1);
        gl2lds16(bsrc0 + kt, bdst0);
        gl2lds16(bsrc1 + kt, bdst1);
        __syncthreads();
        int arow = w * 16 + l16;
        #pragma unroll
        for (int s = 0; s < 2; s++){
            short8 a = *(const short8*)(alds + arow * 64 + (((s * 4 + quad) ^ (l16 & 7)) * 8));
            #pragma unroll
            for (int c = 0; c < 4; c++){
                int brow = c * 16 + l16;
                short8 b = *(const short8*)(blds + brow * 64 + (((s * 4 + quad) ^ (l16 & 7)) * 8));
                acc[c] = __builtin_amdgcn_mfma_f32_16x16x32_bf16(a, b, acc[c], 0, 0, 0);
            }
        }
    }
    int mrow = m0 + w * 16 + quad * 4;
    #pragma unroll
    for (int c = 0; c < 4; c++){
        #pragma unroll
        for (int r = 0; r < 4; r++){
            size_t idx = (size_t)(mrow + r) * N + n0 + c * 16 + l16;
            if (mode == 2) ((short*)C)[idx] = f2bf(acc[c][r]);
            else ((float*)C + (size_t)blockIdx.z * slabstride)[idx] = acc[c][r];
        }
    }
}

// ---------------- dispatch 4: combine e slabs (+biases -> bf16) + vw = sf @ u ----------------
__global__ __launch_bounds__(256) void comb_vw_kernel(const float* __restrict__ es,
        const float* __restrict__ b_rank, const float* __restrict__ b_roi,
        const short* __restrict__ af, const short* __restrict__ uT,
        short* __restrict__ e_bf, float* __restrict__ vwT){
    int bid = blockIdx.x, t = threadIdx.x;
    if (bid < 256){
        int base = (bid * 256 + t) * 4;
        int n = base & (DF - 1);
        float4 s = *(const float4*)(es + base);
        #pragma unroll
        for (int c = 1; c < SPLK; c++){
            float4 tt = *(const float4*)(es + (size_t)c * KP * DF + base);
            s.x += tt.x; s.y += tt.y; s.z += tt.z; s.w += tt.w;
        }
        float4 br = *(const float4*)(b_rank + n);
        float4 bo = *(const float4*)(b_roi + n);
        short4_t o = { f2bf(s.x + br.x + bo.x), f2bf(s.y + br.y + bo.y),
                       f2bf(s.z + br.z + bo.z), f2bf(s.w + br.w + bo.w) };
        *(short4_t*)(e_bf + base) = o;
    } else {
        int vb = bid - 256;
        int w = t >> 6, lane = t & 63, quad = lane >> 4, l16 = lane & 15;
        int m0 = vb * 64 + w * 16;
        f32x4 acc = (f32x4){0.f, 0.f, 0.f, 0.f};
        const short* arow = af + (size_t)(m0 + l16) * 2048 + 1024 + quad * 8;
        const short* brow = uT + (size_t)l16 * DD + quad * 8;
        for (int k0 = 0; k0 < DD; k0 += 32){
            short8 a = *(const short8*)(arow + k0);
            short8 b = *(const short8*)(brow + k0);
            acc = __builtin_amdgcn_mfma_f32_16x16x32_bf16(a, b, acc, 0, 0, 0);
        }
        #pragma unroll
        for (int r = 0; r < 4; r++)
            vwT[(size_t)l16 * KP + m0 + quad * 4 + r] = acc[r];
    }
}

// ---------------- dispatch 6: attention (QK^T, exp, two weighted row-sums) ----------------
// grid (KP/128, NH, NCH) = 1024 blocks; plain stores, fences provided by dispatch boundary.
__global__ __launch_bounds__(256, 4) void attn_kernel(const short* __restrict__ qk,
        const float* __restrict__ vwT,
        float* __restrict__ pl, float* __restrict__ pwl){
    int qt = blockIdx.x, h = blockIdx.y, ch = blockIdx.z;
    int t = threadIdx.x;
    int w = t >> 6, lane = t & 63, quad = lane >> 4, l16 = lane & 15;
    int qb = qt * 128;

    __shared__ __align__(16) short klds[64 * 64];

    short8 aq[2][2];
    #pragma unroll
    for (int tt = 0; tt < 2; tt++){
        const short* qrow = qk + (size_t)(qb + tt * 64 + w * 16 + l16) * 2048 + h * DKK;
        aq[tt][0] = *(const short8*)(qrow + quad * 8);
        aq[tt][1] = *(const short8*)(qrow + 32 + quad * 8);
    }
    float lpart[2][4] = {{0.f,0.f,0.f,0.f},{0.f,0.f,0.f,0.f}};
    float wpart[2][4] = {{0.f,0.f,0.f,0.f},{0.f,0.f,0.f,0.f}};

    int seg0 = w * 128 + lane;
    int row0 = seg0 >> 3, c80 = (seg0 & 7) ^ (row0 & 7);
    int seg1 = seg0 + 64;
    int row1 = seg1 >> 3, c81 = (seg1 & 7) ^ (row1 & 7);
    short* kl0 = klds + (size_t)(w * 128) * 8;
    short* kl1 = klds + (size_t)(w * 128 + 64) * 8;

    for (int m0 = ch * CHUNK; m0 < (ch + 1) * CHUNK; m0 += 64){
        __syncthreads();
        gl2lds16(qk + (size_t)(m0 + row0) * 2048 + 1024 + h * DKK + c80 * 8, kl0);
        gl2lds16(qk + (size_t)(m0 + row1) * 2048 + 1024 + h * DKK + c81 * 8, kl1);
        float vwv[4];
        #pragma unroll
        for (int c = 0; c < 4; c++)
            vwv[c] = vwT[(size_t)h * KP + m0 + c * 16 + l16];
        __syncthreads();

        #pragma unroll
        for (int tt = 0; tt < 2; tt++){
            #pragma unroll
            for (int c = 0; c < 4; c++){
                int r = c * 16 + l16, sw = r & 7;
                short8 b0 = *(const short8*)(klds + r * 64 + (quad ^ sw) * 8);
                short8 b1 = *(const short8*)(klds + r * 64 + ((quad + 4) ^ sw) * 8);
                f32x4 acc = (f32x4){0.f, 0.f, 0.f, 0.f};
                acc = __builtin_amdgcn_mfma_f32_16x16x32_bf16(aq[tt][0], b0, acc, 0, 0, 0);
                acc = __builtin_amdgcn_mfma_f32_16x16x32_bf16(aq[tt][1], b1, acc, 0, 0, 0);
                #pragma unroll
                for (int rr = 0; rr < 4; rr++){
                    float e = __expf(acc[rr]);
                    lpart[tt][rr] += e;
                    wpart[tt][rr] += e * vwv[c];
                }
            }
        }
    }

    #pragma unroll
    for (int tt = 0; tt < 2; tt++){
        #pragma unroll
        for (int rr = 0; rr < 4; rr++){
            float v = lpart[tt][rr], x = wpart[tt][rr];
            v += __shfl_xor(v, 1); x += __shfl_xor(x, 1);
            v += __shfl_xor(v, 2); x += __shfl_xor(x, 2);
            v += __shfl_xor(v, 4); x += __shfl_xor(x, 4);
            v += __shfl_xor(v, 8); x += __shfl_xor(x, 8);
            lpart[tt][rr] = v; wpart[tt][rr] = x;
        }
        if (l16 == 0){
            int qr0 = qb + tt * 64 + w * 16;
            #pragma unroll
            for (int rr = 0; rr < 4; rr++){
                size_t idx = ((size_t)ch * NH + h) * KP + qr0 + quad * 4 + rr;
                pl[idx]  = lpart[tt][rr];
                pwl[idx] = wpart[tt][rr];
            }
        }
    }
}

// ---------------- dispatch 7: final logit + score (1 thread per proposal) ----------------
__global__ __launch_bounds__(256) void final_kernel(const float* __restrict__ dotl,
        const float* __restrict__ pl, const float* __restrict__ pwl,
        const float* __restrict__ sprob, const float* __restrict__ b_logit,
        float* __restrict__ out){
    int pos = blockIdx.x * 256 + threadIdx.x;
    float logit = dotl[pos] + b_logit[0];
    #pragma unroll
    for (int h = 0; h < NH; h++){
        float l = 0.f, x = 0.f;
        #pragma unroll
        for (int c = 0; c < NCH; c++){
            size_t idx = ((size_t)c * NH + h) * KP + pos;
            l += pl[idx]; x += pwl[idx];
        }
        logit += x / l;
    }
    float s1 = 1.f / (1.f + __expf(-logit));
    out[pos] = s1 * sprob[pos];
}

extern "C" void kernel_launch(void* const* d_in, const int* in_sizes, int n_in,
                              void* d_out, int out_size, void* d_ws, size_t ws_size,
                              hipStream_t stream){
    (void)in_sizes; (void)n_in; (void)out_size; (void)ws_size;
    const float* size_scores = (const float*)d_in[0];
    const float* srn     = (const float*)d_in[1];
    const float* sem     = (const float*)d_in[2];
    const float* app     = (const float*)d_in[3];
    const float* mean    = (const float*)d_in[4];
    const float* w_rank  = (const float*)d_in[5];
    const float* b_rank  = (const float*)d_in[6];
    const float* w_roi   = (const float*)d_in[7];
    const float* b_roi   = (const float*)d_in[8];
    const float* Wq      = (const float*)d_in[9];
    const float* Wk      = (const float*)d_in[10];
    const float* Wv      = (const float*)d_in[11];
    const float* w_logit = (const float*)d_in[12];
    const float* b_logit = (const float*)d_in[13];
    float* out = (float*)d_out;

    char* ws = (char*)d_ws;
    size_t off = 0;
    auto alloc = [&](size_t n) -> char* {
        char* pp = ws + off;
        off = (off + n + 255) & ~(size_t)255;
        return pp;
    };
    float*  box   = (float*)  alloc((size_t)KP * 3 * 4);
    int*    label = (int*)    alloc((size_t)KP * 4);
    double* probd = (double*) alloc((size_t)KP * 8);
    double* keyd  = (double*) alloc((size_t)KP * 8);
    float*  sprob = (float*)  alloc((size_t)KP * 4);
    float*  dotl  = (float*)  alloc((size_t)KP * 4);
    short*  wcat  = (short*)  alloc((size_t)DF * 2048 * 2);
    short*  qkT   = (short*)  alloc((size_t)2048 * DF * 2);
    short*  uT    = (short*)  alloc((size_t)NH * DD * 2);
    short*  e_bf  = (short*)  alloc((size_t)KP * DF * 2);
    short*  qk_bf = (short*)  alloc((size_t)KP * 2048 * 2);
    float*  vwT   = (float*)  alloc((size_t)NH * KP * 4);
    float*  pl    = (float*)  alloc((size_t)NCH * NH * KP * 4);
    float*  pwl   = (float*)  alloc((size_t)NCH * NH * KP * 4);
    short*  af    = (short*)  alloc((size_t)KP * 2048 * 2);
    float*  es    = (float*)  alloc((size_t)SPLK * KP * DF * 4);

    prep_convw_kernel<<<200, 256, 0, stream>>>(size_scores, srn, sem, mean,
        w_rank, w_roi, Wq, Wk, Wv, w_logit, box, label, probd, keyd, wcat, qkT, uT);
    rank_af_kernel<<<KP, 256, 0, stream>>>(keyd, label, probd, box, app, w_logit,
        sprob, dotl, af, out);
    gemm_lds<<<dim3(32, 2, SPLK), 256, 0, stream>>>(af, wcat, es, 2048, 2048, DF,
        2048 / SPLK, (size_t)KP * DF, 0);
    comb_vw_kernel<<<288, 256, 0, stream>>>(es, b_rank, b_roi, af, uT, e_bf, vwT);
    gemm_lds<<<dim3(32, 32, 1), 256, 0, stream>>>(e_bf, qkT, qk_bf, DF, DF, 2048, DF, 0, 2);
    attn_kernel<<<dim3(KP / 128, NH, NCH), 256, 0, stream>>>(qk_bf, vwT, pl, pwl);
    final_kernel<<<KP / 256, 256, 0, stream>>>(dotl, pl, pwl, sprob, b_logit, out);
}